// Round 5
// baseline (166.211 us; speedup 1.0000x reference)
//
#include <hip/hip_runtime.h>
#include <hip/hip_bf16.h>
#include <hip/hip_fp16.h>

#define NB 16
#define CCH 64
#define LL 4096   // 64*64
#define DD 1024   // 32*32

typedef _Float16 h8 __attribute__((ext_vector_type(8)));
typedef _Float16 h2 __attribute__((ext_vector_type(2)));
typedef float    f4v __attribute__((ext_vector_type(4)));

#if defined(__has_builtin)
#if __has_builtin(__builtin_amdgcn_fdot2)
#define HAVE_FDOT2 1
#endif
#if __has_builtin(__builtin_amdgcn_exp2f)
#define EXP2F(x) __builtin_amdgcn_exp2f(x)
#endif
#endif
#ifndef EXP2F
#define EXP2F(x) exp2f(x)
#endif

static __device__ __forceinline__ float fdot2f(h2 a, h2 b, float c) {
#ifdef HAVE_FDOT2
    return __builtin_amdgcn_fdot2(a, b, c, false);
#else
    return c + (float)a[0] * (float)b[0] + (float)a[1] * (float)b[1];
#endif
}

#define MFMA16(a, b, c) __builtin_amdgcn_mfma_f32_16x16x32_f16((a), (b), (c), 0, 0, 0)

// ---------------------------------------------------------------------------
// Kernel 1: 1x1 convs + 2x2 maxpool. Emits f16: theta [N][4096][8] (scaled by
// log2(e)), phi [N][1024][8], gT [N][32][1024].
// Block = 256 thr = 4 waves; wave = 16 pixels x 4 channel-quarters
// (lane = cq*16 + p). Cross-cq reduction via shfl_xor(16/32) -- no big LDS.
// Horizontal 2x2-pool half via shfl_xor(1); vertical half via 5 KB LDS.
// Grid = N * 32 rowpairs * 2 colhalves = 1024 blocks -> 16 waves/CU.
// ---------------------------------------------------------------------------
__global__ __launch_bounds__(256) void prep_kernel(
    const float* __restrict__ x,        // [N, 64, 4096]
    const float* __restrict__ w_theta,  // [8, 64]
    const float* __restrict__ w_phi,    // [8, 64]
    const float* __restrict__ w_g,      // [32, 64]
    _Float16* __restrict__ theta_out,   // [N, 4096, 8]  (pre-scaled by log2e)
    _Float16* __restrict__ phi_out,     // [N, 1024, 8]
    _Float16* __restrict__ gT_out)      // [N, 32, 1024]
{
    __shared__ float pool[2][16][41];   // 5.2 KB; stride 41 -> <=2-way conflicts

    const int n    = blockIdx.x >> 6;
    const int rem  = blockIdx.x & 63;
    const int rg   = rem >> 1;          // row-pair 0..31 (rows 2rg, 2rg+1)
    const int half = rem & 1;           // column half (32 cols)
    const int tid  = threadIdx.x;
    const int w    = tid >> 6;          // wave 0..3
    const int lane = tid & 63;
    const int cq   = lane >> 4;         // channel quarter 0..3
    const int p    = lane & 15;         // pixel within wave
    const int r2   = w >> 1;            // row within row-pair (0/1)
    const int c16  = w & 1;             // 16-col chunk within half
    const int row  = rg * 2 + r2;
    const int col  = half * 32 + c16 * 16 + p;
    const int l    = row * 64 + col;

    const float* xp = x + (size_t)n * CCH * LL + l;
    float xv[16];
#pragma unroll
    for (int c = 0; c < 16; ++c) xv[c] = xp[(size_t)(cq * 16 + c) * LL];

    float f48[48];  // [0..7]=theta, [8..15]=phi, [16..47]=g  (partial: 16 ch)
#pragma unroll
    for (int k = 0; k < 8; ++k) {
        float a = 0.f;
        const float* wt = w_theta + k * 64 + cq * 16;
#pragma unroll
        for (int c = 0; c < 16; ++c) a += wt[c] * xv[c];
        f48[k] = a;
    }
#pragma unroll
    for (int k = 0; k < 8; ++k) {
        float a = 0.f;
        const float* wp = w_phi + k * 64 + cq * 16;
#pragma unroll
        for (int c = 0; c < 16; ++c) a += wp[c] * xv[c];
        f48[8 + k] = a;
    }
#pragma unroll
    for (int j = 0; j < 32; ++j) {
        float a = 0.f;
        const float* wg = w_g + j * 64 + cq * 16;
#pragma unroll
        for (int c = 0; c < 16; ++c) a += wg[c] * xv[c];
        f48[16 + j] = a;
    }

    // cross-cq butterfly: lanes p, p+16, p+32, p+48 hold the 4 partials
#pragma unroll
    for (int f = 0; f < 48; ++f) {
        f48[f] += __shfl_xor(f48[f], 16);
        f48[f] += __shfl_xor(f48[f], 32);
    }
    // now every lane holds FULL sums; lane (cq,p) owns features [12cq,12cq+12)

    // theta: features 0..7, all owned by cq==0 lanes -> coalesced h8 stores
    if (cq == 0) {
        h8 tv;
#pragma unroll
        for (int k = 0; k < 8; ++k) tv[k] = (_Float16)(f48[k] * 1.44269504f);
        *(h8*)(theta_out + ((size_t)n * LL + l) * 8) = tv;
    }

    // horizontal pool (cols pair p^1, same wave) then stage vertical to LDS
    {
        const int cp = c16 * 8 + (p >> 1);    // colpair 0..15 within half
#pragma unroll
        for (int j = 0; j < 12; ++j) {
            const int f = cq * 12 + j;
            float v = f48[f];
            float hmax = fmaxf(v, __shfl_xor(v, 1));
            if (f >= 8 && (p & 1) == 0)
                pool[r2][cp][f - 8] = hmax;
        }
    }
    __syncthreads();

    // vertical pool + store: 16 colpairs x 40 features = 640 values
    const int d_base = rg * 32 + half * 16;
    for (int idx = tid; idx < 640; idx += 256) {
        const int f8 = idx >> 4;        // 0..7 phi, 8..39 g
        const int pc = idx & 15;
        float v = fmaxf(pool[0][pc][f8], pool[1][pc][f8]);
        const int d = d_base + pc;
        if (f8 < 8) phi_out[((size_t)n * DD + d) * 8 + f8] = (_Float16)v;
        else        gT_out[((size_t)n * 32 + (f8 - 8)) * DD + d] = (_Float16)v;
    }
}

// ---------------------------------------------------------------------------
// Kernel 2: fused attention via MFMA, 4-way D-split. Block = 256 thr = 4
// waves, all on the same 32 queries; wave h owns d in [h*256, h*256+256).
// Grid = N*128 = 2048 blocks; LDS 17.4 KB, VGPR ~68 -> 7 blocks/CU =
// 28 waves/CU. phi read directly from global (16 KB/image, L1/L2-resident);
// gT B-frags streamed from global; zero barriers in the K-loop.
// Partials combined via LDS (stride 33); out_s aliases red after a barrier.
// ---------------------------------------------------------------------------
__global__ __launch_bounds__(256, 6) void attn_kernel(
    const float*    __restrict__ x,       // [N, 64, 4096]
    const _Float16* __restrict__ theta,   // [N, 4096, 8]
    const _Float16* __restrict__ phi,     // [N, 1024, 8]
    const _Float16* __restrict__ gT,      // [N, 32, 1024]
    const float*    __restrict__ w_o,     // [64, 32]
    const float*    __restrict__ gamma_p, // scalar
    float*          __restrict__ out)     // [N, 64, 4096]
{
    // red [4h][32q][33] f32 = 16896 B | ssum [4][32] = 512 B ; out_s aliases red
    __shared__ __align__(16) char smem[16896 + 512];
    float* red    = (float*)smem;               // [4][32][33]
    float* ssum_s = (float*)(smem + 16896);     // [4][32]
    float* out_s  = (float*)smem;               // [64][33] (aliased, post-barrier)

    const int n    = blockIdx.x >> 7;
    const int lblk = blockIdx.x & 127;
    const int tid  = threadIdx.x;
    const int h    = tid >> 6;            // D-quarter 0..3 (one per wave)
    const int lane = tid & 63;
    const int m16  = lane & 15;
    const int quad = lane >> 4;
    const int l0   = lblk * 32;           // block query base (32 q)

    const _Float16* gT_n  = gT  + (size_t)n * 32 * DD;
    const _Float16* phi_n = phi + (size_t)n * DD * 8;

    // theta rows, two 16-q M-tiles: A[m=lane&15][k=quad*8+j]
    h8 th0 = *(const h8*)(theta + ((size_t)n * LL + l0 + m16) * 8);
    h8 th1 = *(const h8*)(theta + ((size_t)n * LL + l0 + 16 + m16) * 8);
    const h2* t0p = (const h2*)&th0;
    const h2* t1p = (const h2*)&th1;

    // w_o B-frags for this wave's v-pair: och = m16 + 16*(vp*2+i)
    const int vp = h >> 1;
    h8 wof[2];
#pragma unroll
    for (int i = 0; i < 2; ++i) {
        const float* wr = w_o + (size_t)(m16 + 16 * (vp * 2 + i)) * 32 + quad * 8;
        float4 wa = *(const float4*)wr;
        float4 wb = *(const float4*)(wr + 4);
        wof[i][0] = (_Float16)wa.x; wof[i][1] = (_Float16)wa.y;
        wof[i][2] = (_Float16)wa.z; wof[i][3] = (_Float16)wa.w;
        wof[i][4] = (_Float16)wb.x; wof[i][5] = (_Float16)wb.y;
        wof[i][6] = (_Float16)wb.z; wof[i][7] = (_Float16)wb.w;
    }

    f4v c00 = {0.f, 0.f, 0.f, 0.f}, c01 = c00, c10 = c00, c11 = c00;
    float ssum0 = 0.f, ssum1 = 0.f;

    const _Float16* gr0 = gT_n + (size_t)m16 * DD + h * 256 + quad * 8;
    const _Float16* gr1 = gT_n + (size_t)(16 + m16) * DD + h * 256 + quad * 8;
    const _Float16* pr  = phi_n + (size_t)(h * 256 + quad * 8) * 8;

#pragma unroll 2
    for (int c = 0; c < 8; ++c) {
        const int d0 = c * 32;
        h8 b0 = *(const h8*)(gr0 + d0);   // B[k][ch] for ch 0..15
        h8 b1 = *(const h8*)(gr1 + d0);   // ch 16..31
        h8 a0, a1;
#pragma unroll
        for (int j = 0; j < 8; ++j) {
            h8 ph = *(const h8*)(pr + (size_t)(d0 + j) * 8);  // global, L1/L2
            const h2* pp = (const h2*)&ph;
            float s0 = fdot2f(t0p[0], pp[0], 0.f);
            s0 = fdot2f(t0p[1], pp[1], s0);
            s0 = fdot2f(t0p[2], pp[2], s0);
            s0 = fdot2f(t0p[3], pp[3], s0);
            float s1 = fdot2f(t1p[0], pp[0], 0.f);
            s1 = fdot2f(t1p[1], pp[1], s1);
            s1 = fdot2f(t1p[2], pp[2], s1);
            s1 = fdot2f(t1p[3], pp[3], s1);
            float e0 = EXP2F(s0);         // theta pre-scaled by log2e
            float e1 = EXP2F(s1);
            ssum0 += e0; ssum1 += e1;
            a0[j] = (_Float16)e0;
            a1[j] = (_Float16)e1;
        }
        c00 = MFMA16(a0, b0, c00);
        c01 = MFMA16(a0, b1, c01);
        c10 = MFMA16(a1, b0, c10);
        c11 = MFMA16(a1, b1, c11);
    }

    // quarter-D softmax denominators (quads hold disjoint d)
    ssum0 += __shfl_xor(ssum0, 16); ssum0 += __shfl_xor(ssum0, 32);
    ssum1 += __shfl_xor(ssum1, 16); ssum1 += __shfl_xor(ssum1, 32);

    // write partial C (C layout: row = quad*4+r, col = m16) and ssum
    {
        float* rg = red + (size_t)h * 32 * 33;
#pragma unroll
        for (int r = 0; r < 4; ++r) {
            const int rr = quad * 4 + r;
            rg[rr * 33 + m16]             = c00[r];
            rg[rr * 33 + 16 + m16]        = c01[r];
            rg[(16 + rr) * 33 + m16]      = c10[r];
            rg[(16 + rr) * 33 + 16 + m16] = c11[r];
        }
        if (quad == 0) {
            ssum_s[h * 32 + m16]      = ssum0;
            ssum_s[h * 32 + 16 + m16] = ssum1;
        }
    }
    __syncthreads();

    // combine 4 quarters + normalize + pack A-frag.
    // wave h projects M-tile t = h&1: q = t*16 + m16, k = quad*8+j
    const int t = h & 1;
    h8 pa;
    {
        const int q = t * 16 + m16;
        const float* rq = red + q * 33 + quad * 8;
        float ss = ssum_s[q] + ssum_s[32 + q] + ssum_s[64 + q] + ssum_s[96 + q];
        float inv = 1.0f / ss;
#pragma unroll
        for (int j = 0; j < 8; ++j) {
            float sv = rq[j] + rq[32 * 33 + j] + rq[64 * 33 + j] + rq[96 * 33 + j];
            pa[j] = (_Float16)(sv * inv);
        }
    }
    __syncthreads();   // everyone done reading red -> safe to alias out_s

    // projection: D[row=q-local][col=och-local], q = t*16 + quad*4+r
    const f4v zero = {0.f, 0.f, 0.f, 0.f};
#pragma unroll
    for (int i = 0; i < 2; ++i) {
        f4v pv = MFMA16(pa, wof[i], zero);
        const int och = m16 + 16 * (vp * 2 + i);
        float* od = out_s + (size_t)och * 33 + t * 16 + quad * 4;
#pragma unroll
        for (int r = 0; r < 4; ++r) od[r] = pv[r];
    }
    __syncthreads();

    // coalesced store + residual: thread -> och = tid>>2, 8 q starting (tid&3)*8
    const float gamma = gamma_p[0];
    const int soch = tid >> 2;
    const int qoff = (tid & 3) * 8;
    const float* xrow = x   + (size_t)n * CCH * LL + (size_t)soch * LL + l0 + qoff;
    float*       orow = out + (size_t)n * CCH * LL + (size_t)soch * LL + l0 + qoff;
    const float* srow = out_s + (size_t)soch * 33 + qoff;
#pragma unroll
    for (int i = 0; i < 2; ++i) {
        float4 xv = *(const float4*)(xrow + i * 4);
        float4 ov;
        ov.x = xv.x + gamma * srow[i * 4];
        ov.y = xv.y + gamma * srow[i * 4 + 1];
        ov.z = xv.z + gamma * srow[i * 4 + 2];
        ov.w = xv.w + gamma * srow[i * 4 + 3];
        *(float4*)(orow + i * 4) = ov;
    }
}

// ---------------------------------------------------------------------------
extern "C" void kernel_launch(void* const* d_in, const int* in_sizes, int n_in,
                              void* d_out, int out_size, void* d_ws, size_t ws_size,
                              hipStream_t stream) {
    const float* x       = (const float*)d_in[0];
    const float* w_theta = (const float*)d_in[1];
    const float* w_phi   = (const float*)d_in[2];
    const float* w_g     = (const float*)d_in[3];
    const float* w_o     = (const float*)d_in[4];
    const float* gamma   = (const float*)d_in[5];
    float* out = (float*)d_out;

    // ws layout (f16): theta 1 MB | phi 256 KB | gT 1 MB
    _Float16* theta_h = (_Float16*)d_ws;                    // N*L*8
    _Float16* phi_h   = theta_h + (size_t)NB * LL * 8;      // N*D*8
    _Float16* gT_h    = phi_h   + (size_t)NB * DD * 8;      // N*32*D

    prep_kernel<<<1024, 256, 0, stream>>>(x, w_theta, w_phi, w_g,
                                          theta_h, phi_h, gT_h);
    attn_kernel<<<2048, 256, 0, stream>>>(x, theta_h, phi_h, gT_h,
                                          w_o, gamma, out);
}

// Round 6
// 131.496 us; speedup vs baseline: 1.2640x; 1.2640x over previous
//
#include <hip/hip_runtime.h>
#include <hip/hip_bf16.h>
#include <hip/hip_fp16.h>

#define NB 16
#define CCH 64
#define LL 4096   // 64*64
#define DD 1024   // 32*32

typedef _Float16 h8 __attribute__((ext_vector_type(8)));
typedef _Float16 h2 __attribute__((ext_vector_type(2)));
typedef float    f4v __attribute__((ext_vector_type(4)));

#if defined(__has_builtin)
#if __has_builtin(__builtin_amdgcn_fdot2)
#define HAVE_FDOT2 1
#endif
#if __has_builtin(__builtin_amdgcn_exp2f)
#define EXP2F(x) __builtin_amdgcn_exp2f(x)
#endif
#endif
#ifndef EXP2F
#define EXP2F(x) exp2f(x)
#endif

static __device__ __forceinline__ float fdot2f(h2 a, h2 b, float c) {
#ifdef HAVE_FDOT2
    return __builtin_amdgcn_fdot2(a, b, c, false);
#else
    return c + (float)a[0] * (float)b[0] + (float)a[1] * (float)b[1];
#endif
}

#define MFMA16(a, b, c) __builtin_amdgcn_mfma_f32_16x16x32_f16((a), (b), (c), 0, 0, 0)

// ---------------------------------------------------------------------------
// Kernel 1 (REVERTED to R3/R4 version — measured ~30 µs; R5 shfl variant
// regressed). 1x1 convs + 2x2 maxpool. Emits f16: theta [N][4096][8]
// (pre-scaled by log2e), phi [N][1024][8], gT [N][32][1024].
// ---------------------------------------------------------------------------
__global__ __launch_bounds__(256) void prep_kernel(
    const float* __restrict__ x,        // [N, 64, 4096]
    const float* __restrict__ w_theta,  // [8, 64]
    const float* __restrict__ w_phi,    // [8, 64]
    const float* __restrict__ w_g,      // [32, 64]
    _Float16* __restrict__ theta_out,   // [N, 4096, 8]  (pre-scaled by log2e)
    _Float16* __restrict__ phi_out,     // [N, 1024, 8]
    _Float16* __restrict__ gT_out)      // [N, 32, 1024]
{
    __shared__ float part[64][193];     // stride 193 == 1 mod 32, conflict-free

    const int n    = blockIdx.x >> 6;
    const int rem  = blockIdx.x & 63;
    const int rg   = rem >> 1;          // row-pair 0..31
    const int half = rem & 1;           // column half
    const int tid  = threadIdx.x;
    const int cs   = tid >> 6;          // channel quarter (wave-uniform)
    const int pix  = tid & 63;
    const int row  = pix >> 5;
    const int col  = pix & 31;
    const int l    = (rg * 2 + row) * 64 + half * 32 + col;

    const float* xp = x + (size_t)n * CCH * LL + l;
    float xv[16];
#pragma unroll
    for (int c = 0; c < 16; ++c) xv[c] = xp[(size_t)(cs * 16 + c) * LL];

    float f48[48];  // [0..7]=theta, [8..15]=phi, [16..47]=g
#pragma unroll
    for (int k = 0; k < 8; ++k) {
        float a = 0.f;
        const float* w = w_theta + k * 64 + cs * 16;
#pragma unroll
        for (int c = 0; c < 16; ++c) a += w[c] * xv[c];
        f48[k] = a;
    }
#pragma unroll
    for (int k = 0; k < 8; ++k) {
        float a = 0.f;
        const float* w = w_phi + k * 64 + cs * 16;
#pragma unroll
        for (int c = 0; c < 16; ++c) a += w[c] * xv[c];
        f48[8 + k] = a;
    }
#pragma unroll
    for (int j = 0; j < 32; ++j) {
        float a = 0.f;
        const float* w = w_g + j * 64 + cs * 16;
#pragma unroll
        for (int c = 0; c < 16; ++c) a += w[c] * xv[c];
        f48[16 + j] = a;
    }

    {
        float* pp = &part[pix][cs * 48];
#pragma unroll
        for (int f = 0; f < 48; ++f) pp[f] = f48[f];
    }
    __syncthreads();

    float fin[12];
#pragma unroll
    for (int j = 0; j < 12; ++j) {
        int f = cs * 12 + j;
        fin[j] = part[pix][f] + part[pix][48 + f] + part[pix][96 + f] + part[pix][144 + f];
    }

    // theta: f16, pre-scaled by log2(e) so attn can use exp2 directly
    if (cs == 0) {
        h8 tv;
#pragma unroll
        for (int k = 0; k < 8; ++k) tv[k] = (_Float16)(fin[k] * 1.44269504f);
        *(h8*)(theta_out + ((size_t)n * LL + l) * 8) = tv;
    }

#pragma unroll
    for (int j = 0; j < 12; ++j) part[pix][cs * 12 + j] = fin[j];
    __syncthreads();

    // 2x2 maxpool -> f16 stores. idx = f*16 + pc (pc fastest => gT coalesced)
    for (int idx = tid; idx < 40 * 16; idx += 256) {
        int f8 = idx >> 4;              // 0..7 phi, 8..39 g
        int pc = idx & 15;
        int f  = 8 + f8;
        float v = fmaxf(fmaxf(part[2 * pc][f],      part[2 * pc + 1][f]),
                        fmaxf(part[32 + 2 * pc][f], part[33 + 2 * pc][f]));
        int d = rg * 32 + half * 16 + pc;
        if (f8 < 8) phi_out[((size_t)n * DD + d) * 8 + f8] = (_Float16)v;
        else        gT_out[((size_t)n * 32 + (f8 - 8)) * DD + d] = (_Float16)v;
    }
}

// ---------------------------------------------------------------------------
// Kernel 2: fused attention via MFMA, 4-way D-split, phi staged in LDS.
// Block = 256 thr = 4 waves on the same 32 queries; wave h owns d in
// [h*256, h*256+256). Grid = N*128 = 2048 blocks. LDS = 19.5 KB via
// aliasing: phi_s (16 KB, K-loop) -> red [4][32][37] (+ssum) -> out_s
// [32][68]. launch_bounds(256,6) -> 6 blocks/CU = 24 waves/CU.
// All LDS strides chosen for <=2-3-way bank aliasing (free/cheap).
// ---------------------------------------------------------------------------
__global__ __launch_bounds__(256, 6) void attn_kernel(
    const float*    __restrict__ x,       // [N, 64, 4096]
    const _Float16* __restrict__ theta,   // [N, 4096, 8]
    const _Float16* __restrict__ phi,     // [N, 1024, 8]
    const _Float16* __restrict__ gT,      // [N, 32, 1024]
    const float*    __restrict__ w_o,     // [64, 32]
    const float*    __restrict__ gamma_p, // scalar
    float*          __restrict__ out)     // [N, 64, 4096]
{
    // phi_s 16384 B  ALIASED BY  red 4*32*37*4 = 18944 B; ssum at +18944 (512 B)
    // out_s [32][68]*4 = 8704 B aliases red after the combine barrier.
    __shared__ __align__(16) char smem[18944 + 512];
    _Float16* phi_s  = (_Float16*)smem;             // [1024][8] f16
    float*    red    = (float*)smem;                // [4][32][37]
    float*    out_s  = (float*)smem;                // [32][68]
    float*    ssum_s = (float*)(smem + 18944);      // [4][32]

    const int n    = blockIdx.x >> 7;
    const int lblk = blockIdx.x & 127;
    const int tid  = threadIdx.x;
    const int h    = tid >> 6;            // D-quarter 0..3 (one per wave)
    const int lane = tid & 63;
    const int m16  = lane & 15;
    const int quad = lane >> 4;
    const int l0   = lblk * 32;           // block query base (32 q)

    const _Float16* gT_n = gT + (size_t)n * 32 * DD;

    // stage full phi[n] (16 KB) into LDS: 1024 float4s, coalesced
    {
        const float4* ps = (const float4*)(phi + (size_t)n * DD * 8);
        float4* pd = (float4*)phi_s;
#pragma unroll
        for (int i = 0; i < 4; ++i) pd[tid + 256 * i] = ps[tid + 256 * i];
    }

    // theta rows, two 16-q M-tiles: A[m=lane&15][k=quad*8+j]
    h8 th0 = *(const h8*)(theta + ((size_t)n * LL + l0 + m16) * 8);
    h8 th1 = *(const h8*)(theta + ((size_t)n * LL + l0 + 16 + m16) * 8);
    const h2* t0p = (const h2*)&th0;
    const h2* t1p = (const h2*)&th1;

    // w_o B-frags for this wave's och-pair: och = m16 + 16*(vp*2+i)
    const int vp = h >> 1;
    h8 wof[2];
#pragma unroll
    for (int i = 0; i < 2; ++i) {
        const float* wr = w_o + (size_t)(m16 + 16 * (vp * 2 + i)) * 32 + quad * 8;
        float4 wa = *(const float4*)wr;
        float4 wb = *(const float4*)(wr + 4);
        wof[i][0] = (_Float16)wa.x; wof[i][1] = (_Float16)wa.y;
        wof[i][2] = (_Float16)wa.z; wof[i][3] = (_Float16)wa.w;
        wof[i][4] = (_Float16)wb.x; wof[i][5] = (_Float16)wb.y;
        wof[i][6] = (_Float16)wb.z; wof[i][7] = (_Float16)wb.w;
    }

    __syncthreads();   // phi_s ready

    f4v c00 = {0.f, 0.f, 0.f, 0.f}, c01 = c00, c10 = c00, c11 = c00;
    float ssum0 = 0.f, ssum1 = 0.f;

    const _Float16* gr0 = gT_n + (size_t)m16 * DD + h * 256 + quad * 8;
    const _Float16* gr1 = gT_n + (size_t)(16 + m16) * DD + h * 256 + quad * 8;
    const _Float16* pr  = phi_s + (size_t)(h * 256 + quad * 8) * 8;

#pragma unroll 2
    for (int c = 0; c < 8; ++c) {
        const int d0 = c * 32;
        h8 b0 = *(const h8*)(gr0 + d0);   // B[k][ch] for ch 0..15
        h8 b1 = *(const h8*)(gr1 + d0);   // ch 16..31
        h8 a0, a1;
#pragma unroll
        for (int j = 0; j < 8; ++j) {
            h8 ph = *(const h8*)(pr + (size_t)(d0 + j) * 8);  // LDS, quad-broadcast
            const h2* pp = (const h2*)&ph;
            float s0 = fdot2f(t0p[0], pp[0], 0.f);
            s0 = fdot2f(t0p[1], pp[1], s0);
            s0 = fdot2f(t0p[2], pp[2], s0);
            s0 = fdot2f(t0p[3], pp[3], s0);
            float s1 = fdot2f(t1p[0], pp[0], 0.f);
            s1 = fdot2f(t1p[1], pp[1], s1);
            s1 = fdot2f(t1p[2], pp[2], s1);
            s1 = fdot2f(t1p[3], pp[3], s1);
            float e0 = EXP2F(s0);         // theta pre-scaled by log2e
            float e1 = EXP2F(s1);
            ssum0 += e0; ssum1 += e1;
            a0[j] = (_Float16)e0;
            a1[j] = (_Float16)e1;
        }
        c00 = MFMA16(a0, b0, c00);
        c01 = MFMA16(a0, b1, c01);
        c10 = MFMA16(a1, b0, c10);
        c11 = MFMA16(a1, b1, c11);
    }

    // quarter-D softmax denominators (quads hold disjoint d)
    ssum0 += __shfl_xor(ssum0, 16); ssum0 += __shfl_xor(ssum0, 32);
    ssum1 += __shfl_xor(ssum1, 16); ssum1 += __shfl_xor(ssum1, 32);
    if (quad == 0) {
        ssum_s[h * 32 + m16]      = ssum0;   // outside phi_s region: safe now
        ssum_s[h * 32 + 16 + m16] = ssum1;
    }
    __syncthreads();   // ALL waves done reading phi_s -> red may alias it

    // write partial C (C layout: row q = quad*4+r, col ch = m16) into red
    {
        float* rg = red + (size_t)h * 32 * 37;
#pragma unroll
        for (int r = 0; r < 4; ++r) {
            const int rr = quad * 4 + r;
            rg[rr * 37 + m16]             = c00[r];
            rg[rr * 37 + 16 + m16]        = c01[r];
            rg[(16 + rr) * 37 + m16]      = c10[r];
            rg[(16 + rr) * 37 + 16 + m16] = c11[r];
        }
    }
    __syncthreads();

    // combine 4 quarters + normalize + pack A-frag.
    // wave h projects M-tile t = h&1: q = t*16 + m16, k = gch = quad*8+j
    const int t = h & 1;
    h8 pa;
    {
        const int q = t * 16 + m16;
        const float* rq = red + q * 37 + quad * 8;
        float ss = ssum_s[q] + ssum_s[32 + q] + ssum_s[64 + q] + ssum_s[96 + q];
        float inv = 1.0f / ss;
#pragma unroll
        for (int j = 0; j < 8; ++j) {
            float sv = rq[j] + rq[32 * 37 + j] + rq[64 * 37 + j] + rq[96 * 37 + j];
            pa[j] = (_Float16)(sv * inv);
        }
    }
    __syncthreads();   // everyone done reading red -> safe to alias out_s

    // projection: D[row = local q = quad*4+r][col = och], q = t*16 + quad*4+r
    const f4v zero = {0.f, 0.f, 0.f, 0.f};
#pragma unroll
    for (int i = 0; i < 2; ++i) {
        f4v pv = MFMA16(pa, wof[i], zero);
        const int och = m16 + 16 * (vp * 2 + i);
        float* od = out_s + (size_t)(t * 16 + quad * 4) * 68 + och;
#pragma unroll
        for (int r = 0; r < 4; ++r) od[r * 68] = pv[r];
    }
    __syncthreads();

    // coalesced store + residual: thread -> och = tid>>2, 8 q from (tid&3)*8
    const float gamma = gamma_p[0];
    const int soch = tid >> 2;
    const int qoff = (tid & 3) * 8;
    const float* xrow = x   + (size_t)n * CCH * LL + (size_t)soch * LL + l0 + qoff;
    float*       orow = out + (size_t)n * CCH * LL + (size_t)soch * LL + l0 + qoff;
#pragma unroll
    for (int i = 0; i < 2; ++i) {
        float4 xv = *(const float4*)(xrow + i * 4);
        float4 ov;
        ov.x = xv.x + gamma * out_s[(qoff + i * 4)     * 68 + soch];
        ov.y = xv.y + gamma * out_s[(qoff + i * 4 + 1) * 68 + soch];
        ov.z = xv.z + gamma * out_s[(qoff + i * 4 + 2) * 68 + soch];
        ov.w = xv.w + gamma * out_s[(qoff + i * 4 + 3) * 68 + soch];
        *(float4*)(orow + i * 4) = ov;
    }
}

// ---------------------------------------------------------------------------
extern "C" void kernel_launch(void* const* d_in, const int* in_sizes, int n_in,
                              void* d_out, int out_size, void* d_ws, size_t ws_size,
                              hipStream_t stream) {
    const float* x       = (const float*)d_in[0];
    const float* w_theta = (const float*)d_in[1];
    const float* w_phi   = (const float*)d_in[2];
    const float* w_g     = (const float*)d_in[3];
    const float* w_o     = (const float*)d_in[4];
    const float* gamma   = (const float*)d_in[5];
    float* out = (float*)d_out;

    // ws layout (f16): theta 1 MB | phi 256 KB | gT 1 MB
    _Float16* theta_h = (_Float16*)d_ws;                    // N*L*8
    _Float16* phi_h   = theta_h + (size_t)NB * LL * 8;      // N*D*8
    _Float16* gT_h    = phi_h   + (size_t)NB * DD * 8;      // N*32*D

    prep_kernel<<<1024, 256, 0, stream>>>(x, w_theta, w_phi, w_g,
                                          theta_h, phi_h, gT_h);
    attn_kernel<<<2048, 256, 0, stream>>>(x, theta_h, phi_h, gT_h,
                                          w_o, gamma, out);
}